// Round 13
// baseline (509.217 us; speedup 1.0000x reference)
//
#include <hip/hip_runtime.h>
#include <hip/hip_bf16.h>
#include <cstdint>
#include <cstddef>

typedef float  f32x4 __attribute__((ext_vector_type(4)));
typedef short  s16x8 __attribute__((ext_vector_type(8)));

#define NTOK   49
#define CDIM   192
#define HEADS  6
#define SCALE  0.17677669529663689f   // 1/sqrt(32)
#define LOG2E  1.4426950408889634f

// d_ws layout: [biasT: 6*4096 f32 = 98304 B][wq_s: 576*192 u16 = 221184 B][wp_s: 192*192 u16 = 73728 B]
#define WS_BIAS_BYTES  98304
#define WS_WQ_BYTES    221184
#define WS_TOTAL_BYTES (WS_BIAS_BYTES + WS_WQ_BYTES + 73728)

static __device__ __forceinline__ ushort f2bf(float f) {
  __hip_bfloat16 h = __float2bfloat16(f);   // RNE, HW cvt
  union { __hip_bfloat16 h; ushort u; } c; c.h = h;
  return c.u;
}

static __device__ __forceinline__ ushort4 pack4(f32x4 a) {
  union { ushort4 u; __hip_bfloat162 h[2]; } c;
  c.h[0] = __float22bfloat162_rn(make_float2(a[0], a[1]));
  c.h[1] = __float22bfloat162_rn(make_float2(a[2], a[3]));
  return c.u;
}

static __device__ __forceinline__ s16x8 pack8(f32x4 a, f32x4 b) {
  union { s16x8 v; __hip_bfloat162 h[4]; } u;
  u.h[0] = __float22bfloat162_rn(make_float2(a[0], a[1]));
  u.h[1] = __float22bfloat162_rn(make_float2(a[2], a[3]));
  u.h[2] = __float22bfloat162_rn(make_float2(b[0], b[1]));
  u.h[3] = __float22bfloat162_rn(make_float2(b[2], b[3]));
  return u.v;
}

static __device__ __forceinline__ f32x4 mfma_bf16(s16x8 a, s16x8 b, f32x4 c) {
  return __builtin_amdgcn_mfma_f32_16x16x32_bf16(a, b, c, 0, 0, 0);
}

// weights: fragment-major swizzle (n,k) -> ((n>>4)*6+(k>>5))*512 + ((k>>3)&3)*128 + (n&15)*8 + (k&7)
// biasT: fragment-major [h][qt][kt][lane][4]: value for (q=qt*16+(lane&15), key=kt*16+(lane>>4)*4+e)
__global__ void wconv_kernel(const float* __restrict__ qkv_w,
                             const float* __restrict__ proj_w,
                             const float* __restrict__ bias_table,
                             ushort* __restrict__ wqs, ushort* __restrict__ wps,
                             float* __restrict__ biasT) {
  int i = blockIdx.x * 256 + threadIdx.x;
  if (i < 576 * 192) {
    int n = i / 192, k = i % 192;
    int dst = ((n >> 4) * 6 + (k >> 5)) * 512 + ((k >> 3) & 3) * 128 + (n & 15) * 8 + (k & 7);
    wqs[dst] = f2bf(qkv_w[i]);
  }
  if (i < 192 * 192) {
    int n = i / 192, k = i % 192;
    int dst = ((n >> 4) * 6 + (k >> 5)) * 512 + ((k >> 3) & 3) * 128 + (n & 15) * 8 + (k & 7);
    wps[dst] = f2bf(proj_w[i]);
  }
  if (i < HEADS * 4096) {
    int h = i >> 12, r = i & 4095;
    int lane = (r >> 2) & 63, e = r & 3;
    int qt = r >> 10, kt = (r >> 8) & 3;
    int q   = qt * 16 + (lane & 15);
    int key = kt * 16 + (lane >> 4) * 4 + e;
    float v;
    if (key >= NTOK)      v = -1e30f;            // mask baked in
    else if (q >= NTOK)   v = 0.f;               // row unused; keep finite
    else {
      int qd = q / 7, qm = q % 7, kd = key / 7, km = key % 7;
      int ri = (qd - kd + 6) * 13 + (qm - km + 6);
      v = bias_table[ri * 6 + h];
    }
    biasT[i] = v;
  }
}

template <bool WB>
__global__ __launch_bounds__(768, 3)
void wattn_kernel(const float* __restrict__ x,
                  const float* __restrict__ qkv_w, const float* __restrict__ qkv_b,
                  const float* __restrict__ proj_w, const float* __restrict__ proj_b,
                  const float* __restrict__ bias_table,
                  const ushort* __restrict__ wqs, const ushort* __restrict__ wps,
                  const float* __restrict__ biasT,
                  float* __restrict__ out, int nwin) {
  // 2 windows/block, 12 waves -> (3,3,3,3) SIMD packing, 12 waves/CU resident.
  // LDS: 51200 (XB) + 49152 (KS) + 49152 (VT) (+16) = 149,520 B <= 160 KiB
  __shared__ __align__(16) ushort XB[2][64 * 200];      // x (bf16); reused as attn_out
  __shared__ __align__(16) ushort KS[2][HEADS * 2048];  // K frags [h][fi=kt*2+half][lane][4]
  __shared__ __align__(16) ushort VT[2][HEADS * 2048];  // V frags [h][fi=nd*4+kv][lane][4]
  __shared__ __align__(16) float  BL[WB ? 4 : 1024];    // bias_table (fallback path only)

  const int tid  = threadIdx.x;
  const int lane = tid & 63;
  const int wv   = tid >> 6;       // wave 0..11
  const int winl = wv / 6;         // window slot 0/1
  const int w    = wv - winl * 6;  // head id 0..5
  const int l16  = lane & 15;
  const int lk   = lane >> 4;      // 0..3
  const int win  = blockIdx.x * 2 + winl;
  const int h    = w;

  // ---------------- phase 0: stage 2 windows of x -> bf16 LDS (zero pad rows) ---
#pragma unroll
  for (int it = 0; it < 8; ++it) {
    int v = tid + it * 768;               // [0, 6144) covers 2x 64x192 in float4 units
    int wl2 = v / 3072, r = v - wl2 * 3072;
    int row = r / 48, c4 = r - row * 48;
    int wgl = blockIdx.x * 2 + wl2;
    float4 f = {0.f, 0.f, 0.f, 0.f};
    if (row < NTOK && wgl < nwin)
      f = *(const float4*)(x + (size_t)wgl * (NTOK * CDIM) + row * CDIM + c4 * 4);
    union { ushort4 u; __hip_bfloat162 h[2]; } cc;
    cc.h[0] = __float22bfloat162_rn(make_float2(f.x, f.y));
    cc.h[1] = __float22bfloat162_rn(make_float2(f.z, f.w));
    *(ushort4*)&XB[wl2][row * 200 + c4 * 4] = cc.u;
  }
  if constexpr (!WB) {
    for (int v = tid; v < 169 * 6; v += 768) BL[v] = bias_table[v];
  }
  __syncthreads();

  // ---------------- phase 1: QKV GEMM, V -> K -> Q (K/V frags parked in LDS) ----
  // V: mfma(Xfrag, Wfrag) -> D[tok][dim]; Q^T/K^T: mfma(Wfrag, Xfrag) -> D[dim][tok]
  s16x8 bq[4];

  // ---- V pass: epilogue writes fragment-major LDS (dense b64, conflict-free) ---
  {
    f32x4 acc[4][2] = {};
#pragma unroll
    for (int ks = 0; ks < 6; ++ks) {
      const int k0 = ks * 32 + lk * 8;
      s16x8 xa[4];
#pragma unroll
      for (int mt = 0; mt < 4; ++mt)
        xa[mt] = *(const s16x8*)&XB[winl][(mt * 16 + l16) * 200 + k0];
#pragma unroll
      for (int nt2 = 0; nt2 < 2; ++nt2) {
        s16x8 wf;
        if constexpr (WB) {
          wf = *(const s16x8*)&wqs[(((2 * 12 + w * 2 + nt2) * 6 + ks) << 9) + lk * 128 + l16 * 8];
        } else {
          const float* p = qkv_w + (2 * 192 + w * 32 + nt2 * 16 + l16) * 192 + k0;
          float4 f0 = *(const float4*)p, f1 = *(const float4*)(p + 4);
          f32x4 a = {f0.x,f0.y,f0.z,f0.w}, b = {f1.x,f1.y,f1.z,f1.w}; wf = pack8(a, b);
        }
#pragma unroll
        for (int mt = 0; mt < 4; ++mt)
          acc[mt][nt2] = mfma_bf16(xa[mt], wf, acc[mt][nt2]);
      }
    }
    // acc[mt][nt2][i] = V[tok=mt*16+lk*4+i][dim=nt2*16+l16] -> frag fi = nt2*4+mt
#pragma unroll
    for (int nt2 = 0; nt2 < 2; ++nt2) {
      const float vb = qkv_b[2 * 192 + w * 32 + nt2 * 16 + l16];
#pragma unroll
      for (int mt = 0; mt < 4; ++mt) {
        f32x4 a = acc[mt][nt2];
        a[0] += vb; a[1] += vb; a[2] += vb; a[3] += vb;
        *(ushort4*)&VT[winl][((w * 8 + nt2 * 4 + mt) * 64 + lane) * 4] = pack4(a);
      }
    }
  }

  // ---- K pass (NO K-bias: (q+qb)*scale . kb is constant per query -> softmax-invariant)
  {
    f32x4 acc[2][4] = {};
#pragma unroll
    for (int ks = 0; ks < 6; ++ks) {
      const int k0 = ks * 32 + lk * 8;
      s16x8 xa[4];
#pragma unroll
      for (int mt = 0; mt < 4; ++mt)
        xa[mt] = *(const s16x8*)&XB[winl][(mt * 16 + l16) * 200 + k0];
#pragma unroll
      for (int nt2 = 0; nt2 < 2; ++nt2) {
        s16x8 wf;
        if constexpr (WB) {
          wf = *(const s16x8*)&wqs[(((1 * 12 + w * 2 + nt2) * 6 + ks) << 9) + lk * 128 + l16 * 8];
        } else {
          const float* p = qkv_w + (1 * 192 + w * 32 + nt2 * 16 + l16) * 192 + k0;
          float4 f0 = *(const float4*)p, f1 = *(const float4*)(p + 4);
          f32x4 a = {f0.x,f0.y,f0.z,f0.w}, b = {f1.x,f1.y,f1.z,f1.w}; wf = pack8(a, b);
        }
#pragma unroll
        for (int mt = 0; mt < 4; ++mt)
          acc[nt2][mt] = mfma_bf16(wf, xa[mt], acc[nt2][mt]);
      }
    }
    // acc[nt2][mt][i] = K[tok=mt*16+l16][dim=nt2*16+lk*4+i] -> frag fi = mt*2+nt2
#pragma unroll
    for (int nt2 = 0; nt2 < 2; ++nt2)
#pragma unroll
      for (int mt = 0; mt < 4; ++mt)
        *(ushort4*)&KS[winl][((w * 8 + mt * 2 + nt2) * 64 + lane) * 4] = pack4(acc[nt2][mt]);
  }

  // ---- Q pass (produces bq regs) ----
  {
    f32x4 acc[2][4] = {};
#pragma unroll
    for (int ks = 0; ks < 6; ++ks) {
      const int k0 = ks * 32 + lk * 8;
      s16x8 xa[4];
#pragma unroll
      for (int mt = 0; mt < 4; ++mt)
        xa[mt] = *(const s16x8*)&XB[winl][(mt * 16 + l16) * 200 + k0];
#pragma unroll
      for (int nt2 = 0; nt2 < 2; ++nt2) {
        s16x8 wf;
        if constexpr (WB) {
          wf = *(const s16x8*)&wqs[(((0 * 12 + w * 2 + nt2) * 6 + ks) << 9) + lk * 128 + l16 * 8];
        } else {
          const float* p = qkv_w + (0 * 192 + w * 32 + nt2 * 16 + l16) * 192 + k0;
          float4 f0 = *(const float4*)p, f1 = *(const float4*)(p + 4);
          f32x4 a = {f0.x,f0.y,f0.z,f0.w}, b = {f1.x,f1.y,f1.z,f1.w}; wf = pack8(a, b);
        }
#pragma unroll
        for (int mt = 0; mt < 4; ++mt)
          acc[nt2][mt] = mfma_bf16(wf, xa[mt], acc[nt2][mt]);
      }
    }
    const float4 b0 = *(const float4*)&qkv_b[0 * 192 + w * 32 +  0 + lk * 4];
    const float4 b1 = *(const float4*)&qkv_b[0 * 192 + w * 32 + 16 + lk * 4];
#pragma unroll
    for (int t = 0; t < 4; ++t) {
      f32x4 a0 = acc[0][t], a1 = acc[1][t];
      a0[0]=(a0[0]+b0.x)*SCALE; a0[1]=(a0[1]+b0.y)*SCALE; a0[2]=(a0[2]+b0.z)*SCALE; a0[3]=(a0[3]+b0.w)*SCALE;
      a1[0]=(a1[0]+b1.x)*SCALE; a1[1]=(a1[1]+b1.y)*SCALE; a1[2]=(a1[2]+b1.z)*SCALE; a1[3]=(a1[3]+b1.w)*SCALE;
      bq[t] = pack8(a0, a1);
    }
  }
  __syncthreads();   // all XB (x) reads done; XB reusable for attn_out

  // ---------------- phase 2: attention, streamed per 16-query tile --------------
#pragma unroll
  for (int qt = 0; qt < 4; ++qt) {
    f32x4 s[4];
#pragma unroll
    for (int kt = 0; kt < 4; ++kt) {
      union { s16x8 v; uint64_t q[2]; } akc;
      akc.q[0] = *(const volatile uint64_t*)&KS[winl][((w * 8 + kt * 2 + 0) * 64 + lane) * 4];
      akc.q[1] = *(const volatile uint64_t*)&KS[winl][((w * 8 + kt * 2 + 1) * 64 + lane) * 4];
      f32x4 z = {0.f, 0.f, 0.f, 0.f};
      s[kt] = mfma_bf16(akc.v, bq[qt], z);
    }
    float mx = -1e30f;
    if constexpr (WB) {
#pragma unroll
      for (int kt = 0; kt < 4; ++kt) {
        f32x4 b4 = *(const f32x4*)&biasT[h * 4096 + qt * 1024 + kt * 256 + lane * 4];
#pragma unroll
        for (int i = 0; i < 4; ++i) {
          float sv = s[kt][i] + b4[i];
          s[kt][i] = sv;
          mx = fmaxf(mx, sv);
        }
      }
    } else {
      const int q  = qt * 16 + l16;
      const int qd = q / 7, qm = q % 7;
#pragma unroll
      for (int kt = 0; kt < 4; ++kt)
#pragma unroll
        for (int i = 0; i < 4; ++i) {
          const int key = kt * 16 + lk * 4 + i;
          float sv = s[kt][i];
          if (key < NTOK) {
            int kd = key / 7, km = key % 7;
            int ri = (qd - kd + 6) * 13 + (qm - km + 6);
            ri = ri < 0 ? 0 : (ri > 168 ? 168 : ri);
            sv += BL[ri * 6 + h];
          } else sv = -1e30f;
          s[kt][i] = sv;
          mx = fmaxf(mx, sv);
        }
    }
    mx = fmaxf(mx, __shfl_xor(mx, 16));
    mx = fmaxf(mx, __shfl_xor(mx, 32));
    float sum = 0.f;
#pragma unroll
    for (int kt = 0; kt < 4; ++kt)
#pragma unroll
      for (int i = 0; i < 4; ++i) {
        float p = exp2f((s[kt][i] - mx) * LOG2E);
        s[kt][i] = p; sum += p;
      }
    sum += __shfl_xor(sum, 16);
    sum += __shfl_xor(sum, 32);
    const float rinv = 1.f / sum;
#pragma unroll
    for (int kt = 0; kt < 4; ++kt)
#pragma unroll
      for (int i = 0; i < 4; ++i) s[kt][i] *= rinv;

    // PV: A = P (permuted-k over keys), B = V frags from LDS (volatile: no hoist)
    s16x8 pa0 = pack8(s[0], s[1]);
    s16x8 pa1 = pack8(s[2], s[3]);
#pragma unroll
    for (int nd = 0; nd < 2; ++nd) {
      union { s16x8 v; uint64_t q[2]; } b0c, b1c;
      b0c.q[0] = *(const volatile uint64_t*)&VT[winl][((w * 8 + nd * 4 + 0) * 64 + lane) * 4];
      b0c.q[1] = *(const volatile uint64_t*)&VT[winl][((w * 8 + nd * 4 + 1) * 64 + lane) * 4];
      b1c.q[0] = *(const volatile uint64_t*)&VT[winl][((w * 8 + nd * 4 + 2) * 64 + lane) * 4];
      b1c.q[1] = *(const volatile uint64_t*)&VT[winl][((w * 8 + nd * 4 + 3) * 64 + lane) * 4];
      f32x4 z = {0.f, 0.f, 0.f, 0.f};
      f32x4 o = mfma_bf16(pa0, b0c.v, z);
      o = mfma_bf16(pa1, b1c.v, o);
#pragma unroll
      for (int i = 0; i < 4; ++i)
        XB[winl][(qt * 16 + lk * 4 + i) * 200 + h * 32 + nd * 16 + l16] = f2bf(o[i]);
    }
  }
  __syncthreads();   // attn_out fully written to XB

  // ---------------- phase 3: proj GEMM (wave w -> cols [w*32, w*32+32)) --------
  {
    f32x4 pc[4][2] = {};
#pragma unroll
    for (int ks = 0; ks < 6; ++ks) {
      const int k0 = ks * 32 + lk * 8;
      s16x8 a[4];
#pragma unroll
      for (int mt = 0; mt < 4; ++mt)
        a[mt] = *(const s16x8*)&XB[winl][(mt * 16 + l16) * 200 + k0];
#pragma unroll
      for (int nt = 0; nt < 2; ++nt) {
        s16x8 b;
        if constexpr (WB) {
          b = *(const s16x8*)&wps[(((w * 2 + nt) * 6 + ks) << 9) + lk * 128 + l16 * 8];
        } else {
          const int n = w * 32 + nt * 16 + l16;
          const float* p = proj_w + n * 192 + k0;
          float4 f0 = *(const float4*)p, f1 = *(const float4*)(p + 4);
          f32x4 fa = {f0.x,f0.y,f0.z,f0.w}, fb = {f1.x,f1.y,f1.z,f1.w};
          b = pack8(fa, fb);
        }
#pragma unroll
        for (int mt = 0; mt < 4; ++mt)
          pc[mt][nt] = mfma_bf16(a[mt], b, pc[mt][nt]);
      }
    }
    if (win < nwin) {
#pragma unroll
      for (int nt = 0; nt < 2; ++nt) {
        const int n = w * 32 + nt * 16 + l16;
        const float pbias = proj_b[n];
#pragma unroll
        for (int mt = 0; mt < 4; ++mt)
#pragma unroll
          for (int i = 0; i < 4; ++i) {
            const int row = mt * 16 + lk * 4 + i;
            if (row < NTOK)
              out[((size_t)win * NTOK + row) * CDIM + n] = pc[mt][nt][i] + pbias;
          }
      }
    }
  }
}

extern "C" void kernel_launch(void* const* d_in, const int* in_sizes, int n_in,
                              void* d_out, int out_size, void* d_ws, size_t ws_size,
                              hipStream_t stream) {
  const float* x          = (const float*)d_in[0];
  const float* qkv_w      = (const float*)d_in[1];
  const float* qkv_b      = (const float*)d_in[2];
  const float* proj_w     = (const float*)d_in[3];
  const float* proj_b     = (const float*)d_in[4];
  const float* bias_table = (const float*)d_in[5];
  float* out = (float*)d_out;

  const int nwin = in_sizes[0] / (NTOK * CDIM);   // 8192
  const int nblk = (nwin + 1) / 2;

  if (ws_size >= WS_TOTAL_BYTES) {
    float*  biasT = (float*)d_ws;
    ushort* wqs   = (ushort*)((char*)d_ws + WS_BIAS_BYTES);
    ushort* wps   = (ushort*)((char*)d_ws + WS_BIAS_BYTES + WS_WQ_BYTES);
    wconv_kernel<<<dim3(432), dim3(256), 0, stream>>>(qkv_w, proj_w, bias_table, wqs, wps, biasT);
    wattn_kernel<true><<<dim3(nblk), dim3(768), 0, stream>>>(
        x, qkv_w, qkv_b, proj_w, proj_b, bias_table, wqs, wps, biasT, out, nwin);
  } else {
    wattn_kernel<false><<<dim3(nblk), dim3(768), 0, stream>>>(
        x, qkv_w, qkv_b, proj_w, proj_b, bias_table, nullptr, nullptr, nullptr, out, nwin);
  }
}

// Round 14
// 408.978 us; speedup vs baseline: 1.2451x; 1.2451x over previous
//
#include <hip/hip_runtime.h>
#include <hip/hip_bf16.h>
#include <cstdint>
#include <cstddef>

typedef float  f32x4 __attribute__((ext_vector_type(4)));
typedef short  s16x8 __attribute__((ext_vector_type(8)));

#define NTOK   49
#define CDIM   192
#define HEADS  6
#define SCALE  0.17677669529663689f   // 1/sqrt(32)
#define LOG2E  1.4426950408889634f
#define SCL2   (0.17677669529663689f * 1.4426950408889634f)  // SCALE*LOG2E

// d_ws layout: [biasT: 6*4096 f32 = 98304 B][wq_s: 576*192 u16 = 221184 B][wp_s: 192*192 u16 = 73728 B]
#define WS_BIAS_BYTES  98304
#define WS_WQ_BYTES    221184
#define WS_TOTAL_BYTES (WS_BIAS_BYTES + WS_WQ_BYTES + 73728)

static __device__ __forceinline__ ushort f2bf(float f) {
  __hip_bfloat16 h = __float2bfloat16(f);   // RNE, HW cvt
  union { __hip_bfloat16 h; ushort u; } c; c.h = h;
  return c.u;
}

static __device__ __forceinline__ s16x8 pack8(f32x4 a, f32x4 b) {
  union { s16x8 v; __hip_bfloat162 h[4]; } u;
  u.h[0] = __float22bfloat162_rn(make_float2(a[0], a[1]));
  u.h[1] = __float22bfloat162_rn(make_float2(a[2], a[3]));
  u.h[2] = __float22bfloat162_rn(make_float2(b[0], b[1]));
  u.h[3] = __float22bfloat162_rn(make_float2(b[2], b[3]));
  return u.v;
}

static __device__ __forceinline__ f32x4 mfma_bf16(s16x8 a, s16x8 b, f32x4 c) {
  return __builtin_amdgcn_mfma_f32_16x16x32_bf16(a, b, c, 0, 0, 0);
}

// weights: fragment-major swizzle (n,k) -> ((n>>4)*6+(k>>5))*512 + ((k>>3)&3)*128 + (n&15)*8 + (k&7)
// biasT: fragment-major [h][qt][kt][lane][4], PREMULTIPLIED by LOG2E, key-mask baked in
__global__ void wconv_kernel(const float* __restrict__ qkv_w,
                             const float* __restrict__ proj_w,
                             const float* __restrict__ bias_table,
                             ushort* __restrict__ wqs, ushort* __restrict__ wps,
                             float* __restrict__ biasT) {
  int i = blockIdx.x * 256 + threadIdx.x;
  if (i < 576 * 192) {
    int n = i / 192, k = i % 192;
    int dst = ((n >> 4) * 6 + (k >> 5)) * 512 + ((k >> 3) & 3) * 128 + (n & 15) * 8 + (k & 7);
    wqs[dst] = f2bf(qkv_w[i]);
  }
  if (i < 192 * 192) {
    int n = i / 192, k = i % 192;
    int dst = ((n >> 4) * 6 + (k >> 5)) * 512 + ((k >> 3) & 3) * 128 + (n & 15) * 8 + (k & 7);
    wps[dst] = f2bf(proj_w[i]);
  }
  if (i < HEADS * 4096) {
    int h = i >> 12, r = i & 4095;
    int lane = (r >> 2) & 63, e = r & 3;
    int qt = r >> 10, kt = (r >> 8) & 3;
    int q   = qt * 16 + (lane & 15);
    int key = kt * 16 + (lane >> 4) * 4 + e;
    float v;
    if (key >= NTOK)      v = -1e30f;            // mask baked in
    else if (q >= NTOK)   v = 0.f;               // row unused; keep finite
    else {
      int qd = q / 7, qm = q % 7, kd = key / 7, km = key % 7;
      int ri = (qd - kd + 6) * 13 + (qm - km + 6);
      v = bias_table[ri * 6 + h] * LOG2E;        // log2-domain
    }
    biasT[i] = v;
  }
}

template <bool WB>
__global__ __launch_bounds__(768, 3)
void wattn_kernel(const float* __restrict__ x,
                  const float* __restrict__ qkv_w, const float* __restrict__ qkv_b,
                  const float* __restrict__ proj_w, const float* __restrict__ proj_b,
                  const float* __restrict__ bias_table,
                  const ushort* __restrict__ wqs, const ushort* __restrict__ wps,
                  const float* __restrict__ biasT,
                  float* __restrict__ out, int nwin) {
  // 2 windows/block, 12 waves -> (3,3,3,3) SIMD packing, 12 waves/CU resident.
  // LDS: 2*25600 (+16) = 51,216 B
  __shared__ __align__(16) ushort XB[2][64 * 200];   // x (bf16); reused as attn_out
  __shared__ __align__(16) float  BL[WB ? 4 : 1024]; // bias_table (fallback path only)

  const int tid  = threadIdx.x;
  const int lane = tid & 63;
  const int wv   = tid >> 6;       // wave 0..11
  const int winl = wv / 6;         // window slot 0/1
  const int w    = wv - winl * 6;  // head id 0..5
  const int l16  = lane & 15;
  const int lk   = lane >> 4;      // 0..3
  const int win  = blockIdx.x * 2 + winl;
  const int h    = w;

  // ---------------- phase 0: stage 2 windows of x -> bf16 LDS (zero pad rows) ---
#pragma unroll
  for (int it = 0; it < 8; ++it) {
    int v = tid + it * 768;               // [0, 6144) covers 2x 64x192 in float4 units
    int wl2 = v / 3072, r = v - wl2 * 3072;
    int row = r / 48, c4 = r - row * 48;
    int wgl = blockIdx.x * 2 + wl2;
    float4 f = {0.f, 0.f, 0.f, 0.f};
    if (row < NTOK && wgl < nwin)
      f = *(const float4*)(x + (size_t)wgl * (NTOK * CDIM) + row * CDIM + c4 * 4);
    union { ushort4 u; __hip_bfloat162 h[2]; } cc;
    cc.h[0] = __float22bfloat162_rn(make_float2(f.x, f.y));
    cc.h[1] = __float22bfloat162_rn(make_float2(f.z, f.w));
    *(ushort4*)&XB[wl2][row * 200 + c4 * 4] = cc.u;
  }
  if constexpr (!WB) {
    for (int v = tid; v < 169 * 6; v += 768) BL[v] = bias_table[v];
  }
  __syncthreads();

  // ---------------- phase 1: QKV GEMM in 2 passes (fits 170-reg bucket, no spill)
  // Pass A: Q^T + K^T (64 AGPR acc); Pass B: V (32 AGPR acc, carries bq+ak).
  // Q^T/K^T: mfma(Wfrag, Xfrag) -> D[dim][tok]; V: mfma(Xfrag, Wfrag) -> D[tok][dim]
  s16x8 bq[4], ak[4], bv[2][2];

  // ---- Pass A: Q and K ----
  {
    f32x4 qacc[2][4] = {};   // [dim-tile][tok-tile]
    f32x4 kacc[2][4] = {};
#pragma unroll
    for (int ks = 0; ks < 6; ++ks) {
      const int k0 = ks * 32 + lk * 8;
      s16x8 xa[4];
#pragma unroll
      for (int mt = 0; mt < 4; ++mt)
        xa[mt] = *(const s16x8*)&XB[winl][(mt * 16 + l16) * 200 + k0];
#pragma unroll
      for (int nt2 = 0; nt2 < 2; ++nt2) {
        s16x8 wqf, wkf;
        if constexpr (WB) {
          const int lo = lk * 128 + l16 * 8;
          wqf = *(const s16x8*)&wqs[(((0 * 12 + w * 2 + nt2) * 6 + ks) << 9) + lo];
          wkf = *(const s16x8*)&wqs[(((1 * 12 + w * 2 + nt2) * 6 + ks) << 9) + lo];
        } else {
          const int nq = w * 32 + nt2 * 16 + l16;
          const float* p;
          p = qkv_w + (0 * 192 + nq) * 192 + k0;
          { float4 f0 = *(const float4*)p, f1 = *(const float4*)(p + 4);
            f32x4 a = {f0.x,f0.y,f0.z,f0.w}, b = {f1.x,f1.y,f1.z,f1.w}; wqf = pack8(a, b); }
          p = qkv_w + (1 * 192 + nq) * 192 + k0;
          { float4 f0 = *(const float4*)p, f1 = *(const float4*)(p + 4);
            f32x4 a = {f0.x,f0.y,f0.z,f0.w}, b = {f1.x,f1.y,f1.z,f1.w}; wkf = pack8(a, b); }
        }
#pragma unroll
        for (int mt = 0; mt < 4; ++mt) {
          qacc[nt2][mt] = mfma_bf16(wqf, xa[mt], qacc[nt2][mt]);
          kacc[nt2][mt] = mfma_bf16(wkf, xa[mt], kacc[nt2][mt]);
        }
      }
    }
    // epilogue Q -> bq (fold SCALE*LOG2E; log2-domain softmax)
    {
      const float4 b0 = *(const float4*)&qkv_b[0 * 192 + w * 32 +  0 + lk * 4];
      const float4 b1 = *(const float4*)&qkv_b[0 * 192 + w * 32 + 16 + lk * 4];
#pragma unroll
      for (int t = 0; t < 4; ++t) {
        f32x4 a0 = qacc[0][t], a1 = qacc[1][t];
        a0[0]=(a0[0]+b0.x)*SCL2; a0[1]=(a0[1]+b0.y)*SCL2; a0[2]=(a0[2]+b0.z)*SCL2; a0[3]=(a0[3]+b0.w)*SCL2;
        a1[0]=(a1[0]+b1.x)*SCL2; a1[1]=(a1[1]+b1.y)*SCL2; a1[2]=(a1[2]+b1.z)*SCL2; a1[3]=(a1[3]+b1.w)*SCL2;
        bq[t] = pack8(a0, a1);
      }
    }
    // epilogue K -> ak (NO K-bias: q.kb is per-query constant -> softmax-invariant)
#pragma unroll
    for (int t = 0; t < 4; ++t)
      ak[t] = pack8(kacc[0][t], kacc[1][t]);
  }

  // ---- Pass B: V (carries bq + ak) ----
  {
    f32x4 vacc[4][2] = {};   // [tok-tile][dim-tile]
#pragma unroll
    for (int ks = 0; ks < 6; ++ks) {
      const int k0 = ks * 32 + lk * 8;
      s16x8 xa[4];
#pragma unroll
      for (int mt = 0; mt < 4; ++mt)
        xa[mt] = *(const s16x8*)&XB[winl][(mt * 16 + l16) * 200 + k0];
#pragma unroll
      for (int nt2 = 0; nt2 < 2; ++nt2) {
        s16x8 wf;
        if constexpr (WB) {
          wf = *(const s16x8*)&wqs[(((2 * 12 + w * 2 + nt2) * 6 + ks) << 9) + lk * 128 + l16 * 8];
        } else {
          const float* p = qkv_w + (2 * 192 + w * 32 + nt2 * 16 + l16) * 192 + k0;
          float4 f0 = *(const float4*)p, f1 = *(const float4*)(p + 4);
          f32x4 a = {f0.x,f0.y,f0.z,f0.w}, b = {f1.x,f1.y,f1.z,f1.w}; wf = pack8(a, b);
        }
#pragma unroll
        for (int mt = 0; mt < 4; ++mt)
          vacc[mt][nt2] = mfma_bf16(xa[mt], wf, vacc[mt][nt2]);
      }
    }
#pragma unroll
    for (int nd = 0; nd < 2; ++nd) {
      const float vb = qkv_b[2 * 192 + w * 32 + nd * 16 + l16];
      f32x4 v0 = vacc[0][nd], v1 = vacc[1][nd], v2 = vacc[2][nd], v3 = vacc[3][nd];
#pragma unroll
      for (int i = 0; i < 4; ++i) { v0[i]+=vb; v1[i]+=vb; v2[i]+=vb; v3[i]+=vb; }
      bv[nd][0] = pack8(v0, v1);
      bv[nd][1] = pack8(v2, v3);
    }
  }
  __syncthreads();   // all XB (x) reads done; XB reusable for attn_out

  // ---------------- phase 2: attention, streamed per 16-query tile --------------
  // S^T = K · Q^T (log2 domain): per qt, s[kt] with col=l16=query, row=lk*4+i=key
#pragma unroll
  for (int qt = 0; qt < 4; ++qt) {
    f32x4 s[4];
#pragma unroll
    for (int kt = 0; kt < 4; ++kt) {
      f32x4 z = {0.f, 0.f, 0.f, 0.f};
      s[kt] = mfma_bf16(ak[kt], bq[qt], z);
    }
    float mx = -1e30f;
    if constexpr (WB) {
#pragma unroll
      for (int kt = 0; kt < 4; ++kt) {
        f32x4 b4 = *(const f32x4*)&biasT[h * 4096 + qt * 1024 + kt * 256 + lane * 4];
#pragma unroll
        for (int i = 0; i < 4; ++i) {
          float sv = s[kt][i] + b4[i];
          s[kt][i] = sv;
          mx = fmaxf(mx, sv);
        }
      }
    } else {
      const int q  = qt * 16 + l16;
      const int qd = q / 7, qm = q % 7;
#pragma unroll
      for (int kt = 0; kt < 4; ++kt)
#pragma unroll
        for (int i = 0; i < 4; ++i) {
          const int key = kt * 16 + lk * 4 + i;
          float sv = s[kt][i];
          if (key < NTOK) {
            int kd = key / 7, km = key % 7;
            int ri = (qd - kd + 6) * 13 + (qm - km + 6);
            ri = ri < 0 ? 0 : (ri > 168 ? 168 : ri);
            sv += BL[ri * 6 + h] * LOG2E;
          } else sv = -1e30f;
          s[kt][i] = sv;
          mx = fmaxf(mx, sv);
        }
    }
    mx = fmaxf(mx, __shfl_xor(mx, 16));
    mx = fmaxf(mx, __shfl_xor(mx, 32));
    float sum = 0.f;
#pragma unroll
    for (int kt = 0; kt < 4; ++kt)
#pragma unroll
      for (int i = 0; i < 4; ++i) {
        float p = exp2f(s[kt][i] - mx);   // already log2-domain
        s[kt][i] = p; sum += p;
      }
    sum += __shfl_xor(sum, 16);
    sum += __shfl_xor(sum, 32);
    const float rinv = 1.f / sum;
#pragma unroll
    for (int kt = 0; kt < 4; ++kt)
#pragma unroll
      for (int i = 0; i < 4; ++i) s[kt][i] *= rinv;

    // PV for this qt: A = P (permuted-k over keys), B = V (same permuted-k)
    s16x8 pa0 = pack8(s[0], s[1]);
    s16x8 pa1 = pack8(s[2], s[3]);
#pragma unroll
    for (int nd = 0; nd < 2; ++nd) {
      f32x4 z = {0.f, 0.f, 0.f, 0.f};
      f32x4 o = mfma_bf16(pa0, bv[nd][0], z);
      o = mfma_bf16(pa1, bv[nd][1], o);
#pragma unroll
      for (int i = 0; i < 4; ++i)
        XB[winl][(qt * 16 + lk * 4 + i) * 200 + h * 32 + nd * 16 + l16] = f2bf(o[i]);
    }
  }
  __syncthreads();   // attn_out fully written to XB

  // ---------------- phase 3: proj GEMM (wave w -> cols [w*32, w*32+32)) --------
  {
    f32x4 pc[4][2] = {};
#pragma unroll
    for (int ks = 0; ks < 6; ++ks) {
      const int k0 = ks * 32 + lk * 8;
      s16x8 a[4];
#pragma unroll
      for (int mt = 0; mt < 4; ++mt)
        a[mt] = *(const s16x8*)&XB[winl][(mt * 16 + l16) * 200 + k0];
#pragma unroll
      for (int nt = 0; nt < 2; ++nt) {
        s16x8 b;
        if constexpr (WB) {
          b = *(const s16x8*)&wps[(((w * 2 + nt) * 6 + ks) << 9) + lk * 128 + l16 * 8];
        } else {
          const int n = w * 32 + nt * 16 + l16;
          const float* p = proj_w + n * 192 + k0;
          float4 f0 = *(const float4*)p, f1 = *(const float4*)(p + 4);
          f32x4 fa = {f0.x,f0.y,f0.z,f0.w}, fb = {f1.x,f1.y,f1.z,f1.w};
          b = pack8(fa, fb);
        }
#pragma unroll
        for (int mt = 0; mt < 4; ++mt)
          pc[mt][nt] = mfma_bf16(a[mt], b, pc[mt][nt]);
      }
    }
    if (win < nwin) {
#pragma unroll
      for (int nt = 0; nt < 2; ++nt) {
        const int n = w * 32 + nt * 16 + l16;
        const float pbias = proj_b[n];
#pragma unroll
        for (int mt = 0; mt < 4; ++mt)
#pragma unroll
          for (int i = 0; i < 4; ++i) {
            const int row = mt * 16 + lk * 4 + i;
            if (row < NTOK)
              out[((size_t)win * NTOK + row) * CDIM + n] = pc[mt][nt][i] + pbias;
          }
      }
    }
  }
}

extern "C" void kernel_launch(void* const* d_in, const int* in_sizes, int n_in,
                              void* d_out, int out_size, void* d_ws, size_t ws_size,
                              hipStream_t stream) {
  const float* x          = (const float*)d_in[0];
  const float* qkv_w      = (const float*)d_in[1];
  const float* qkv_b      = (const float*)d_in[2];
  const float* proj_w     = (const float*)d_in[3];
  const float* proj_b     = (const float*)d_in[4];
  const float* bias_table = (const float*)d_in[5];
  float* out = (float*)d_out;

  const int nwin = in_sizes[0] / (NTOK * CDIM);   // 8192
  const int nblk = (nwin + 1) / 2;

  if (ws_size >= WS_TOTAL_BYTES) {
    float*  biasT = (float*)d_ws;
    ushort* wqs   = (ushort*)((char*)d_ws + WS_BIAS_BYTES);
    ushort* wps   = (ushort*)((char*)d_ws + WS_BIAS_BYTES + WS_WQ_BYTES);
    wconv_kernel<<<dim3(432), dim3(256), 0, stream>>>(qkv_w, proj_w, bias_table, wqs, wps, biasT);
    wattn_kernel<true><<<dim3(nblk), dim3(768), 0, stream>>>(
        x, qkv_w, qkv_b, proj_w, proj_b, bias_table, wqs, wps, biasT, out, nwin);
  } else {
    wattn_kernel<false><<<dim3(nblk), dim3(768), 0, stream>>>(
        x, qkv_w, qkv_b, proj_w, proj_b, bias_table, nullptr, nullptr, nullptr, out, nwin);
  }
}